// Round 1
// baseline (110.600 us; speedup 1.0000x reference)
//
#include <hip/hip_runtime.h>
#include <math.h>

// MultiPool: gather + CSR-segmented sum/mean/min/max, concat on dim 1.
// Inputs: embs [N=500000, D=128] f32, batches [T=1048576] i32, lens [B+1=65537] i32.
// Output: [B=65536, 4*D=512] f32  (sum | mean | min | max).
//
// Layout: 32 lanes per segment, lane owns 4 consecutive columns (float4).
// A segment's 32 lanes together read one contiguous 512B row per gather ->
// fully coalesced. Index loads hit the same address across the lane group ->
// wave broadcast. No LDS, no atomics.

#ifndef INFINITY
#define INFINITY __builtin_huge_valf()
#endif

constexpr int D = 128;
constexpr int LANES_PER_SEG = 32;   // D/4 columns per lane group

__global__ __launch_bounds__(256) void multipool_kernel(
    const float* __restrict__ embs,
    const int*   __restrict__ batches,
    const int*   __restrict__ lens,
    float*       __restrict__ out,
    int B)
{
    const int tid  = blockIdx.x * blockDim.x + threadIdx.x;
    const int seg  = tid >> 5;         // /32
    const int lane = tid & 31;
    if (seg >= B) return;

    const int start = lens[seg];
    const int end   = lens[seg + 1];
    const int cnt   = end - start;

    const int col = lane * 4;

    float4 s  = make_float4(0.f, 0.f, 0.f, 0.f);
    float4 mn = make_float4( INFINITY,  INFINITY,  INFINITY,  INFINITY);
    float4 mx = make_float4(-INFINITY, -INFINITY, -INFINITY, -INFINITY);

    for (int i = start; i < end; ++i) {
        const int row = batches[i];
        const float4 v = *reinterpret_cast<const float4*>(
            embs + (size_t)row * D + col);
        s.x += v.x; s.y += v.y; s.z += v.z; s.w += v.w;
        mn.x = fminf(mn.x, v.x); mn.y = fminf(mn.y, v.y);
        mn.z = fminf(mn.z, v.z); mn.w = fminf(mn.w, v.w);
        mx.x = fmaxf(mx.x, v.x); mx.y = fmaxf(mx.y, v.y);
        mx.z = fmaxf(mx.z, v.z); mx.w = fmaxf(mx.w, v.w);
    }

    const float inv = 1.0f / fmaxf((float)cnt, 1.0f);
    const float4 mean = make_float4(s.x * inv, s.y * inv, s.z * inv, s.w * inv);

    float* ob = out + (size_t)seg * (4 * D);
    *reinterpret_cast<float4*>(ob + col)           = s;
    *reinterpret_cast<float4*>(ob + D + col)       = mean;
    *reinterpret_cast<float4*>(ob + 2 * D + col)   = mn;
    *reinterpret_cast<float4*>(ob + 3 * D + col)   = mx;
}

extern "C" void kernel_launch(void* const* d_in, const int* in_sizes, int n_in,
                              void* d_out, int out_size, void* d_ws, size_t ws_size,
                              hipStream_t stream) {
    const float* embs    = (const float*)d_in[0];
    const int*   batches = (const int*)d_in[1];
    const int*   lens    = (const int*)d_in[2];
    float*       out     = (float*)d_out;

    const int B = in_sizes[2] - 1;   // lens has B+1 entries

    const int threads = 256;
    const long long total_threads = (long long)B * LANES_PER_SEG;
    const int blocks = (int)((total_threads + threads - 1) / threads);

    multipool_kernel<<<blocks, threads, 0, stream>>>(embs, batches, lens, out, B);
}

// Round 3
// 101.003 us; speedup vs baseline: 1.0950x; 1.0950x over previous
//
#include <hip/hip_runtime.h>
#include <math.h>

// MultiPool: gather + CSR-segmented sum/mean/min/max, concat on dim 1.
// Inputs: embs [N=500000, D=128] f32, batches [T=1048576] i32, lens [B+1=65537] i32.
// Output: [B=65536, 4*D=512] f32  (sum | mean | min | max).
//
// Round 1 -> 2: latency-bound serial chain fixed by preloading all 16 indices
// (one coalesced transaction per 32-lane group), __shfl broadcast, and issuing
// all 16 float4 gathers back-to-back (16 outstanding vmem/wave).
// Round 2 fix: __builtin_nontemporal_store needs a native vector type, not
// HIP_vector_type<float,4> — use ext_vector_type(4) float for the stores.

#ifndef INFINITY
#define INFINITY __builtin_huge_valf()
#endif

typedef float f32x4 __attribute__((ext_vector_type(4)));

constexpr int D = 128;
constexpr int LANES_PER_SEG = 32;   // D/4 columns per lane group
constexpr int SEGLEN = 16;

__global__ __launch_bounds__(256) void multipool_kernel(
    const float* __restrict__ embs,
    const int*   __restrict__ batches,
    const int*   __restrict__ lens,
    float*       __restrict__ out,
    int B)
{
    const int tid   = blockIdx.x * blockDim.x + threadIdx.x;
    const int seg   = tid >> 5;        // /32
    const int lane  = tid & 31;        // lane within segment group
    const int wlane = threadIdx.x & 63;
    const int gbase = wlane & 32;      // first wave-lane of this 32-lane group
    if (seg >= B) return;

    const int start = lens[seg];
    const int end   = lens[seg + 1];
    const int cnt   = end - start;

    const int col = lane * 4;

    f32x4 s  = {0.f, 0.f, 0.f, 0.f};
    f32x4 mn = { INFINITY,  INFINITY,  INFINITY,  INFINITY};
    f32x4 mx = {-INFINITY, -INFINITY, -INFINITY, -INFINITY};

    if (cnt == SEGLEN) {
        // Fast path (uniform segments): preload 16 indices, 16 gathers in flight.
        const int myidx = batches[start + (lane & 15)];

        f32x4 v[SEGLEN];
#pragma unroll
        for (int i = 0; i < SEGLEN; ++i) {
            const int row = __shfl(myidx, gbase + i);
            v[i] = *reinterpret_cast<const f32x4*>(
                embs + (size_t)row * D + col);
        }
#pragma unroll
        for (int i = 0; i < SEGLEN; ++i) {
            s += v[i];
            mn.x = fminf(mn.x, v[i].x); mn.y = fminf(mn.y, v[i].y);
            mn.z = fminf(mn.z, v[i].z); mn.w = fminf(mn.w, v[i].w);
            mx.x = fmaxf(mx.x, v[i].x); mx.y = fmaxf(mx.y, v[i].y);
            mx.z = fmaxf(mx.z, v[i].z); mx.w = fmaxf(mx.w, v[i].w);
        }
    } else {
        // Generic fallback (not hit for the benchmarked inputs).
        for (int i = start; i < end; ++i) {
            const int row = batches[i];
            const f32x4 v = *reinterpret_cast<const f32x4*>(
                embs + (size_t)row * D + col);
            s += v;
            mn.x = fminf(mn.x, v.x); mn.y = fminf(mn.y, v.y);
            mn.z = fminf(mn.z, v.z); mn.w = fminf(mn.w, v.w);
            mx.x = fmaxf(mx.x, v.x); mx.y = fmaxf(mx.y, v.y);
            mx.z = fmaxf(mx.z, v.z); mx.w = fmaxf(mx.w, v.w);
        }
    }

    const float inv = 1.0f / fmaxf((float)cnt, 1.0f);
    const f32x4 mean = s * inv;

    float* ob = out + (size_t)seg * (4 * D);
    __builtin_nontemporal_store(s,    reinterpret_cast<f32x4*>(ob + col));
    __builtin_nontemporal_store(mean, reinterpret_cast<f32x4*>(ob + D + col));
    __builtin_nontemporal_store(mn,   reinterpret_cast<f32x4*>(ob + 2 * D + col));
    __builtin_nontemporal_store(mx,   reinterpret_cast<f32x4*>(ob + 3 * D + col));
}

extern "C" void kernel_launch(void* const* d_in, const int* in_sizes, int n_in,
                              void* d_out, int out_size, void* d_ws, size_t ws_size,
                              hipStream_t stream) {
    const float* embs    = (const float*)d_in[0];
    const int*   batches = (const int*)d_in[1];
    const int*   lens    = (const int*)d_in[2];
    float*       out     = (float*)d_out;

    const int B = in_sizes[2] - 1;   // lens has B+1 entries

    const int threads = 256;
    const long long total_threads = (long long)B * LANES_PER_SEG;
    const int blocks = (int)((total_threads + threads - 1) / threads);

    multipool_kernel<<<blocks, threads, 0, stream>>>(embs, batches, lens, out, B);
}